// Round 6
// baseline (198.649 us; speedup 1.0000x reference)
//
#include <hip/hip_runtime.h>
#include <cstdint>

// Self-attention, B=2 S=2048 D=1024 H=16 hd=64, fp32 in/out, bf16 MFMA internals.
// Pipeline: convert -> fused QKV GEMM (K pre-scaled by 0.125*log2e, V stored
// transposed [B,H,d,S]) -> flash attention (S^T orientation, no-max softmax,
// DMA double-buffered K/V staging, in-register P^T via permuted contraction,
// O^T accumulation) -> output GEMM (128x64 tiles, 512 blocks).

typedef unsigned short ush;
typedef __bf16 bf16x8 __attribute__((ext_vector_type(8)));
typedef float f32x4 __attribute__((ext_vector_type(4)));
typedef ush u16x8 __attribute__((ext_vector_type(8)));
typedef ush u16x4 __attribute__((ext_vector_type(4)));
typedef unsigned int u32x4 __attribute__((ext_vector_type(4)));

__device__ __forceinline__ ush f2bf(float f) {
  unsigned int u = __float_as_uint(f);
  u += 0x7fffu + ((u >> 16) & 1u);   // RNE
  return (ush)(u >> 16);
}

// pack bf16(b)<<16 | bf16(a), round-half-up, 3 VALU ops
__device__ __forceinline__ unsigned int pack2bf_ru(float a, float b) {
  unsigned int ua = __float_as_uint(a) + 0x8000u;
  unsigned int ub = __float_as_uint(b) + 0x8000u;
  return __builtin_amdgcn_perm(ub, ua, 0x07060302u);
}

__device__ __forceinline__ bf16x8 bc8(u16x8 v) {
  return __builtin_bit_cast(bf16x8, v);
}

// async 16B global->LDS (DMA, wave-uniform LDS base + lane*16)
__device__ __forceinline__ void async16(const void* g, void* l) {
  __builtin_amdgcn_global_load_lds(
      (const __attribute__((address_space(1))) unsigned int*)(uintptr_t)g,
      (__attribute__((address_space(3))) unsigned int*)(uintptr_t)l, 16, 0, 0);
}

// ---------------- convert fp32 -> bf16 (x + 4 weights) ----------------
__global__ __launch_bounds__(256) void convert_kernel(
    const float* __restrict__ x, const float* __restrict__ Wq,
    const float* __restrict__ Wk, const float* __restrict__ Wv,
    const float* __restrict__ Wo,
    ush* __restrict__ xb, ush* __restrict__ Wqb, ush* __restrict__ Wkb,
    ush* __restrict__ Wvb, ush* __restrict__ Wob)
{
  int tid = blockIdx.x * 256 + threadIdx.x;
  int base = tid * 4;
  const float* src; ush* dst; int idx;
  if (base < 4194304) { src = x; dst = xb; idx = base; }
  else {
    int r = base - 4194304;
    int seg = r >> 20;
    idx = r & 1048575;
    src = seg == 0 ? Wq : seg == 1 ? Wk : seg == 2 ? Wv : Wo;
    dst = seg == 0 ? Wqb : seg == 1 ? Wkb : seg == 2 ? Wvb : Wob;
  }
  float4 f = *(const float4*)(src + idx);
  u16x4 u = { f2bf(f.x), f2bf(f.y), f2bf(f.z), f2bf(f.w) };
  *(u16x4*)(dst + idx) = u;
}

// ---------------- 128x128 NT bf16 GEMM core, K=1024, BK=64 ----------------
__device__ __forceinline__ void gemm128_core(
    const ush* __restrict__ gA, const ush* __restrict__ gB,
    int m0, int n0, ush* lA, ush* lB, f32x4 (&acc)[4][4])
{
  const int t = threadIdx.x, w = t >> 6, lane = t & 63;
  const int l15 = lane & 15, quad = lane >> 4;
  const int wm = (w >> 1) * 64, wn = (w & 1) * 64;
#pragma unroll
  for (int i = 0; i < 4; ++i)
#pragma unroll
    for (int j = 0; j < 4; ++j) acc[i][j] = (f32x4){0.f, 0.f, 0.f, 0.f};

  for (int kt = 0; kt < 1024; kt += 64) {
#pragma unroll
    for (int i = 0; i < 4; ++i) {           // A tile: 128x64 = 1024 chunks
      int j = i * 256 + w * 64 + lane;
      int row = j >> 3, cc = (j & 7) ^ (row & 7);
      async16(gA + (size_t)(m0 + row) * 1024 + kt + cc * 8,
              lA + (i * 256 + w * 64) * 8);
    }
#pragma unroll
    for (int i = 0; i < 4; ++i) {           // B tile
      int j = i * 256 + w * 64 + lane;
      int row = j >> 3, cc = (j & 7) ^ (row & 7);
      async16(gB + (size_t)(n0 + row) * 1024 + kt + cc * 8,
              lB + (i * 256 + w * 64) * 8);
    }
    __syncthreads();
#pragma unroll
    for (int kf = 0; kf < 2; ++kf) {
      bf16x8 aF[4], bF[4];
#pragma unroll
      for (int mt = 0; mt < 4; ++mt) {
        int row = wm + mt * 16 + l15;
        aF[mt] = bc8(*(const u16x8*)(lA + row * 64 + (((kf * 4 + quad) ^ (row & 7)) * 8)));
      }
#pragma unroll
      for (int nt = 0; nt < 4; ++nt) {
        int row = wn + nt * 16 + l15;
        bF[nt] = bc8(*(const u16x8*)(lB + row * 64 + (((kf * 4 + quad) ^ (row & 7)) * 8)));
      }
#pragma unroll
      for (int mt = 0; mt < 4; ++mt)
#pragma unroll
        for (int nt = 0; nt < 4; ++nt)
          acc[mt][nt] = __builtin_amdgcn_mfma_f32_16x16x32_bf16(
              aF[mt], bF[nt], acc[mt][nt], 0, 0, 0);
    }
    __syncthreads();
  }
}

// ---------------- fused QKV projection ----------------
// grid = 3 * 256 blocks. Q,K as [B,H,S,64]; V transposed as [B,H,64,S].
// K output pre-scaled by 0.125*log2(e) so attention scores feed exp2 raw.
__global__ __launch_bounds__(256, 2) void qkv_gemm(
    const ush* __restrict__ xb, const ush* __restrict__ Wqb,
    const ush* __restrict__ Wkb, const ush* __restrict__ Wvb,
    const float* __restrict__ bq, const float* __restrict__ bk,
    const float* __restrict__ bv,
    ush* __restrict__ q, ush* __restrict__ k, ush* __restrict__ vt)
{
  int bid = blockIdx.x;
  int wsel = bid >> 8;
  int rem = bid & 255;
  int m0 = (rem & 31) * 128;
  int n0 = (rem >> 5) * 128;
  const ush* gB = wsel == 0 ? Wqb : wsel == 1 ? Wkb : Wvb;
  const float* bias = wsel == 0 ? bq : wsel == 1 ? bk : bv;
  const float oscale = wsel == 1 ? 0.180336880f : 1.0f;  // 0.125*log2e on K

  __shared__ alignas(16) ush lA[128 * 64];
  __shared__ alignas(16) ush lB[128 * 64];
  f32x4 acc[4][4];
  gemm128_core(xb, gB, m0, n0, lA, lB, acc);

  const int t = threadIdx.x, w = t >> 6, lane = t & 63;
  const int l15 = lane & 15, quad = lane >> 4;
  const int wm = (w >> 1) * 64, wn = (w & 1) * 64;
  if (wsel == 2) {
    // V^T: [B,H,64(d),2048(s)]; 4 consecutive s per lane -> u16x4 stores
#pragma unroll
    for (int nt = 0; nt < 4; ++nt) {
      int o = n0 + wn + nt * 16 + l15;
      float bl = bias[o];
      int h = o >> 6, d = o & 63;
#pragma unroll
      for (int mt = 0; mt < 4; ++mt) {
        int tb = m0 + wm + mt * 16 + quad * 4;
        int b = tb >> 11, s = tb & 2047;
        u16x4 pk = { f2bf(acc[mt][nt][0] + bl), f2bf(acc[mt][nt][1] + bl),
                     f2bf(acc[mt][nt][2] + bl), f2bf(acc[mt][nt][3] + bl) };
        *(u16x4*)(vt + (size_t)(((b * 16 + h) * 64) + d) * 2048 + s) = pk;
      }
    }
  } else {
    ush* dst = wsel == 0 ? q : k;
#pragma unroll
    for (int nt = 0; nt < 4; ++nt) {
      int o = n0 + wn + nt * 16 + l15;
      float bl = bias[o];
      int h = o >> 6, d = o & 63;
#pragma unroll
      for (int mt = 0; mt < 4; ++mt)
#pragma unroll
        for (int r = 0; r < 4; ++r) {
          int token = m0 + wm + mt * 16 + quad * 4 + r;
          int b = token >> 11, s = token & 2047;
          dst[(size_t)(((b * 16 + h) * 2048) + s) * 64 + d] =
              f2bf((acc[mt][nt][r] + bl) * oscale);
        }
    }
  }
}

// ---------------- flash attention (S^T, in-register P^T) ----------------
// 1024 blocks = 32 bh x 32 q-tiles of 64 rows; 4 waves, 16 q each.
// Block swizzle: all 32 q-tiles of one bh share blockIdx%8 -> same XCD L2.
// S^T = K·Q^T gives C[key][query]; PV computed as O^T = V^T·P^T with the
// contraction keys permuted (key = ks*32 + quad*4 + (j&3) + (j>>2)*16) so the
// packed exp outputs ARE the B-operand fragments: no LDS round-trip for P.
__global__ __launch_bounds__(256, 4) void attn_kernel(
    const ush* __restrict__ Q, const ush* __restrict__ K,
    const ush* __restrict__ VT, ush* __restrict__ O)
{
  const int bid = blockIdx.x;
  const int bh = (bid & 7) * 4 + (bid >> 8);   // same bh -> same XCD residue
  const int qt = (bid >> 3) & 31;
  const ush* qb = Q + (size_t)bh * 2048 * 64;
  const ush* kb = K + (size_t)bh * 2048 * 64;
  const ush* vtb = VT + (size_t)bh * 64 * 2048;   // [d][s]
  const int t = threadIdx.x, w = t >> 6, lane = t & 63;
  const int l15 = lane & 15, quad = lane >> 4;
  const int q0 = qt * 64 + w * 16;        // this wave's 16 queries

  __shared__ alignas(16) ush lK[2][64 * 64];     // [key][d], swizzled chunks
  __shared__ alignas(16) ush lV[2][64 * 64];     // [d][key], swizzled chunks

  // staging geometry: this thread stages chunks {t, t+256}; swizzle in source
  const int r0 = t >> 3;
  const int c0 = (t & 7) ^ (r0 & 7);
  const ush* kSrc0 = kb + (size_t)r0 * 64 + c0 * 8;
  const ush* kSrc1 = kb + (size_t)(r0 + 32) * 64 + c0 * 8;
  const ush* vSrc0 = vtb + (size_t)r0 * 2048 + c0 * 8;
  const ush* vSrc1 = vtb + (size_t)(r0 + 32) * 2048 + c0 * 8;

  // Q fragments (B-operand: n=q=l15, k=d) stay in registers
  bf16x8 qF[2];
#pragma unroll
  for (int kf = 0; kf < 2; ++kf)
    qF[kf] = bc8(*(const u16x8*)(qb + (size_t)(q0 + l15) * 64 + kf * 32 + quad * 8));

  float li = 0.f;
  f32x4 accO[4];                          // O^T: [d=dt*16+quad*4+r][q=l15]
#pragma unroll
  for (int dt = 0; dt < 4; ++dt) accO[dt] = (f32x4){0.f, 0.f, 0.f, 0.f};

  // V A-operand read geometry (loop-invariant): row d = dt*16+l15,
  // chunk (ks*4 + 2g + (quad>>1)) ^ (l15&7), 8B half (quad&1)
  const int sw = l15 & 7;
  const int qh = (quad & 1) * 4;
  const int qg = quad >> 1;

  // prologue: DMA tile 0 into buffer 0
  async16(kSrc0, lK[0] + t * 8);
  async16(kSrc1, lK[0] + (t + 256) * 8);
  async16(vSrc0, lV[0] + t * 8);
  async16(vSrc1, lV[0] + (t + 256) * 8);
  __syncthreads();                       // vmcnt drain = DMA complete

  for (int it = 0; it < 32; ++it) {
    const int cur = it & 1, nxt = cur ^ 1;
    if (it + 1 < 32) {                   // DMA next tile while computing this one
      const size_t ko = (size_t)(it + 1) * 64 * 64;   // K advances by rows
      const int vo = (it + 1) * 64;                   // V^T advances by cols
      async16(kSrc0 + ko, lK[nxt] + t * 8);
      async16(kSrc1 + ko, lK[nxt] + (t + 256) * 8);
      async16(vSrc0 + vo, lV[nxt] + t * 8);
      async16(vSrc1 + vo, lV[nxt] + (t + 256) * 8);
    }
    const ush* lk = lK[cur];
    const ush* lv = lV[cur];

    // S^T = K·Q^T : A=K (m=key), B=Q (n=q). C: row=key=mt*16+quad*4+r, col=q=l15
    f32x4 sc[4];
#pragma unroll
    for (int mt = 0; mt < 4; ++mt) sc[mt] = (f32x4){0.f, 0.f, 0.f, 0.f};
#pragma unroll
    for (int kf = 0; kf < 2; ++kf) {
#pragma unroll
      for (int mt = 0; mt < 4; ++mt) {
        int row = mt * 16 + l15;
        bf16x8 aK = bc8(*(const u16x8*)(lk + row * 64 + (((kf * 4 + quad) ^ (row & 7)) * 8)));
        sc[mt] = __builtin_amdgcn_mfma_f32_16x16x32_bf16(aK, qF[kf], sc[mt], 0, 0, 0);
      }
    }

    // softmax: raw v_exp (args bounded); packed exps form P^T B-fragments
    float rs = 0.f;
    f32x4 p[4];
#pragma unroll
    for (int mt = 0; mt < 4; ++mt)
#pragma unroll
      for (int r = 0; r < 4; ++r) {
        p[mt][r] = __builtin_amdgcn_exp2f(sc[mt][r]);
        rs += p[mt][r];
      }
    rs += __shfl_xor(rs, 16);
    rs += __shfl_xor(rs, 32);
    li += rs;

    // PV: O^T = V^T · P^T. ks in {0,1} covers key windows of 32 (subtile pair).
#pragma unroll
    for (int ks = 0; ks < 2; ++ks) {
      u32x4 bw = { pack2bf_ru(p[2 * ks][0],     p[2 * ks][1]),
                   pack2bf_ru(p[2 * ks][2],     p[2 * ks][3]),
                   pack2bf_ru(p[2 * ks + 1][0], p[2 * ks + 1][1]),
                   pack2bf_ru(p[2 * ks + 1][2], p[2 * ks + 1][3]) };
      bf16x8 bP = __builtin_bit_cast(bf16x8, bw);
      int c1 = ((ks * 4 + qg) ^ sw) * 8 + qh;
      int c2 = ((ks * 4 + 2 + qg) ^ sw) * 8 + qh;
#pragma unroll
      for (int dt = 0; dt < 4; ++dt) {
        const ush* base = lv + (dt * 16 + l15) * 64;
        u16x4 a0 = *(const u16x4*)(base + c1);
        u16x4 a1 = *(const u16x4*)(base + c2);
        u16x8 av = { a0[0], a0[1], a0[2], a0[3], a1[0], a1[1], a1[2], a1[3] };
        accO[dt] = __builtin_amdgcn_mfma_f32_16x16x32_bf16(bc8(av), bP, accO[dt], 0, 0, 0);
      }
    }
    __syncthreads();   // all reads of cur done + next-tile DMA drained
  }

  // epilogue: O[q][d] = accO^T/li, packed u16x4 stores to [B,S,D]
  const int b = bh >> 4, h = bh & 15;
  const float linv = __builtin_amdgcn_rcpf(li);   // li complete for query l15
  const int s = q0 + l15;
#pragma unroll
  for (int dt = 0; dt < 4; ++dt) {
    u16x4 pk = { f2bf(accO[dt][0] * linv), f2bf(accO[dt][1] * linv),
                 f2bf(accO[dt][2] * linv), f2bf(accO[dt][3] * linv) };
    *(u16x4*)(O + (size_t)(b * 2048 + s) * 1024 + h * 64 + dt * 16 + quad * 4) = pk;
  }
}

// ---------------- output projection (fp32 out, 128x64 tiles) ----------------
__global__ __launch_bounds__(256, 2) void out_gemm(
    const ush* __restrict__ ab, const ush* __restrict__ Wob,
    const float* __restrict__ bo, float* __restrict__ out)
{
  int rem = blockIdx.x;                  // 512 blocks: 32 m x 16 n
  int m0 = (rem & 31) * 128;
  int n0 = (rem >> 5) * 64;
  __shared__ alignas(16) ush lA[128 * 64];
  __shared__ alignas(16) ush lB[64 * 64];

  const int t = threadIdx.x, w = t >> 6, lane = t & 63;
  const int l15 = lane & 15, quad = lane >> 4;
  const int wm = (w >> 1) * 64, wn = (w & 1) * 32;
  f32x4 acc[4][2];
#pragma unroll
  for (int i = 0; i < 4; ++i)
#pragma unroll
    for (int j = 0; j < 2; ++j) acc[i][j] = (f32x4){0.f, 0.f, 0.f, 0.f};

  for (int kt = 0; kt < 1024; kt += 64) {
#pragma unroll
    for (int i = 0; i < 4; ++i) {         // A tile: 128x64 = 1024 chunks
      int j = i * 256 + t;
      int row = j >> 3, cc = (j & 7) ^ (row & 7);
      async16(ab + (size_t)(m0 + row) * 1024 + kt + cc * 8, lA + j * 8);
    }
#pragma unroll
    for (int i = 0; i < 2; ++i) {         // B tile: 64x64 = 512 chunks
      int j = i * 256 + t;
      int row = j >> 3, cc = (j & 7) ^ (row & 7);
      async16(Wob + (size_t)(n0 + row) * 1024 + kt + cc * 8, lB + j * 8);
    }
    __syncthreads();
#pragma unroll
    for (int kf = 0; kf < 2; ++kf) {
      bf16x8 aF[4], bF[2];
#pragma unroll
      for (int mt = 0; mt < 4; ++mt) {
        int row = wm + mt * 16 + l15;
        aF[mt] = bc8(*(const u16x8*)(lA + row * 64 + (((kf * 4 + quad) ^ (row & 7)) * 8)));
      }
#pragma unroll
      for (int nt = 0; nt < 2; ++nt) {
        int row = wn + nt * 16 + l15;
        bF[nt] = bc8(*(const u16x8*)(lB + row * 64 + (((kf * 4 + quad) ^ (row & 7)) * 8)));
      }
#pragma unroll
      for (int mt = 0; mt < 4; ++mt)
#pragma unroll
        for (int nt = 0; nt < 2; ++nt)
          acc[mt][nt] = __builtin_amdgcn_mfma_f32_16x16x32_bf16(
              aF[mt], bF[nt], acc[mt][nt], 0, 0, 0);
    }
    __syncthreads();
  }

#pragma unroll
  for (int nt = 0; nt < 2; ++nt) {
    int o = n0 + wn + nt * 16 + l15;
    float bl = bo[o];
#pragma unroll
    for (int mt = 0; mt < 4; ++mt)
#pragma unroll
      for (int r = 0; r < 4; ++r) {
        int token = m0 + wm + mt * 16 + quad * 4 + r;
        out[(size_t)token * 1024 + o] = acc[mt][nt][r] + bl;
      }
  }
}

extern "C" void kernel_launch(void* const* d_in, const int* in_sizes, int n_in,
                              void* d_out, int out_size, void* d_ws, size_t ws_size,
                              hipStream_t stream)
{
  const float* x  = (const float*)d_in[0];
  const float* Wq = (const float*)d_in[1];
  const float* bq = (const float*)d_in[2];
  const float* Wk = (const float*)d_in[3];
  const float* bk = (const float*)d_in[4];
  const float* Wv = (const float*)d_in[5];
  const float* bv = (const float*)d_in[6];
  const float* Wo = (const float*)d_in[7];
  const float* bo = (const float*)d_in[8];
  float* out = (float*)d_out;

  char* ws = (char*)d_ws;
  ush* xb  = (ush*)(ws);                      // 8 MiB  [4096 x 1024]
  ush* Wqb = (ush*)(ws + (size_t)( 8u << 20));// 2 MiB each
  ush* Wkb = (ush*)(ws + (size_t)(10u << 20));
  ush* Wvb = (ush*)(ws + (size_t)(12u << 20));
  ush* Wob = (ush*)(ws + (size_t)(14u << 20));
  ush* qb  = (ush*)(ws + (size_t)(16u << 20));// 8 MiB [B,H,S,64]
  ush* kb  = (ush*)(ws + (size_t)(24u << 20));
  ush* vtb = (ush*)(ws + (size_t)(32u << 20));// 8 MiB [B,H,64,S] (V^T)
  ush* ab  = (ush*)(ws + (size_t)(40u << 20));// 8 MiB [B,S,D] attn out (bf16)

  convert_kernel<<<8192, 256, 0, stream>>>(x, Wq, Wk, Wv, Wo,
                                           xb, Wqb, Wkb, Wvb, Wob);
  qkv_gemm<<<768, 256, 0, stream>>>(xb, Wqb, Wkb, Wvb, bq, bk, bv, qb, kb, vtb);
  attn_kernel<<<1024, 256, 0, stream>>>(qb, kb, vtb, ab);
  out_gemm<<<512, 256, 0, stream>>>(ab, Wob, bo, out);
}

// Round 7
// 186.922 us; speedup vs baseline: 1.0627x; 1.0627x over previous
//
#include <hip/hip_runtime.h>
#include <cstdint>

// Self-attention, B=2 S=2048 D=1024 H=16 hd=64, fp32 in/out, bf16 MFMA internals.
// Pipeline: convert -> fused QKV GEMM (K pre-scaled by 0.125*log2e; V stored
// transposed [B,H,d,S] with key-bit-permuted columns) -> flash attention
// (S^T orientation, no-max softmax, DMA double-buffered staging, in-register
// P^T, b128 V fragments, 32 queries/wave) -> output GEMM (128x128).

typedef unsigned short ush;
typedef __bf16 bf16x8 __attribute__((ext_vector_type(8)));
typedef float f32x4 __attribute__((ext_vector_type(4)));
typedef ush u16x8 __attribute__((ext_vector_type(8)));
typedef ush u16x4 __attribute__((ext_vector_type(4)));
typedef unsigned int u32x4 __attribute__((ext_vector_type(4)));

__device__ __forceinline__ ush f2bf(float f) {
  unsigned int u = __float_as_uint(f);
  u += 0x7fffu + ((u >> 16) & 1u);   // RNE
  return (ush)(u >> 16);
}

// pack bf16(b)<<16 | bf16(a), round-half-up, 3 VALU ops
__device__ __forceinline__ unsigned int pack2bf_ru(float a, float b) {
  unsigned int ua = __float_as_uint(a) + 0x8000u;
  unsigned int ub = __float_as_uint(b) + 0x8000u;
  return __builtin_amdgcn_perm(ub, ua, 0x07060302u);
}

__device__ __forceinline__ bf16x8 bc8(u16x8 v) {
  return __builtin_bit_cast(bf16x8, v);
}

// async 16B global->LDS (DMA, wave-uniform LDS base + lane*16)
__device__ __forceinline__ void async16(const void* g, void* l) {
  __builtin_amdgcn_global_load_lds(
      (const __attribute__((address_space(1))) unsigned int*)(uintptr_t)g,
      (__attribute__((address_space(3))) unsigned int*)(uintptr_t)l, 16, 0, 0);
}

// ---------------- convert fp32 -> bf16 (x + 4 weights) ----------------
__global__ __launch_bounds__(256) void convert_kernel(
    const float* __restrict__ x, const float* __restrict__ Wq,
    const float* __restrict__ Wk, const float* __restrict__ Wv,
    const float* __restrict__ Wo,
    ush* __restrict__ xb, ush* __restrict__ Wqb, ush* __restrict__ Wkb,
    ush* __restrict__ Wvb, ush* __restrict__ Wob)
{
  int tid = blockIdx.x * 256 + threadIdx.x;
  int base = tid * 4;
  const float* src; ush* dst; int idx;
  if (base < 4194304) { src = x; dst = xb; idx = base; }
  else {
    int r = base - 4194304;
    int seg = r >> 20;
    idx = r & 1048575;
    src = seg == 0 ? Wq : seg == 1 ? Wk : seg == 2 ? Wv : Wo;
    dst = seg == 0 ? Wqb : seg == 1 ? Wkb : seg == 2 ? Wvb : Wob;
  }
  float4 f = *(const float4*)(src + idx);
  u16x4 u = { f2bf(f.x), f2bf(f.y), f2bf(f.z), f2bf(f.w) };
  *(u16x4*)(dst + idx) = u;
}

// ---------------- 128x128 NT bf16 GEMM core, K=1024, BK=64 ----------------
__device__ __forceinline__ void gemm128_core(
    const ush* __restrict__ gA, const ush* __restrict__ gB,
    int m0, int n0, ush* lA, ush* lB, f32x4 (&acc)[4][4])
{
  const int t = threadIdx.x, w = t >> 6, lane = t & 63;
  const int l15 = lane & 15, quad = lane >> 4;
  const int wm = (w >> 1) * 64, wn = (w & 1) * 64;
#pragma unroll
  for (int i = 0; i < 4; ++i)
#pragma unroll
    for (int j = 0; j < 4; ++j) acc[i][j] = (f32x4){0.f, 0.f, 0.f, 0.f};

  for (int kt = 0; kt < 1024; kt += 64) {
#pragma unroll
    for (int i = 0; i < 4; ++i) {           // A tile: 128x64 = 1024 chunks
      int j = i * 256 + w * 64 + lane;
      int row = j >> 3, cc = (j & 7) ^ (row & 7);
      async16(gA + (size_t)(m0 + row) * 1024 + kt + cc * 8,
              lA + (i * 256 + w * 64) * 8);
    }
#pragma unroll
    for (int i = 0; i < 4; ++i) {           // B tile
      int j = i * 256 + w * 64 + lane;
      int row = j >> 3, cc = (j & 7) ^ (row & 7);
      async16(gB + (size_t)(n0 + row) * 1024 + kt + cc * 8,
              lB + (i * 256 + w * 64) * 8);
    }
    __syncthreads();
#pragma unroll
    for (int kf = 0; kf < 2; ++kf) {
      bf16x8 aF[4], bF[4];
#pragma unroll
      for (int mt = 0; mt < 4; ++mt) {
        int row = wm + mt * 16 + l15;
        aF[mt] = bc8(*(const u16x8*)(lA + row * 64 + (((kf * 4 + quad) ^ (row & 7)) * 8)));
      }
#pragma unroll
      for (int nt = 0; nt < 4; ++nt) {
        int row = wn + nt * 16 + l15;
        bF[nt] = bc8(*(const u16x8*)(lB + row * 64 + (((kf * 4 + quad) ^ (row & 7)) * 8)));
      }
#pragma unroll
      for (int mt = 0; mt < 4; ++mt)
#pragma unroll
        for (int nt = 0; nt < 4; ++nt)
          acc[mt][nt] = __builtin_amdgcn_mfma_f32_16x16x32_bf16(
              aF[mt], bF[nt], acc[mt][nt], 0, 0, 0);
    }
    __syncthreads();
  }
}

// ---------------- fused QKV projection ----------------
// grid = 3 * 256 blocks. Q,K as [B,H,S,64]; V transposed as [B,H,64,S] with
// columns permuted within each 64-token window: p = [s5][s3][s2][s4][s1][s0]
// so the attention PV A-fragment is one contiguous 16B LDS read.
// K output pre-scaled by 0.125*log2(e) so attention scores feed exp2 raw.
__global__ __launch_bounds__(256, 2) void qkv_gemm(
    const ush* __restrict__ xb, const ush* __restrict__ Wqb,
    const ush* __restrict__ Wkb, const ush* __restrict__ Wvb,
    const float* __restrict__ bq, const float* __restrict__ bk,
    const float* __restrict__ bv,
    ush* __restrict__ q, ush* __restrict__ k, ush* __restrict__ vt)
{
  int bid = blockIdx.x;
  int wsel = bid >> 8;
  int rem = bid & 255;
  int m0 = (rem & 31) * 128;
  int n0 = (rem >> 5) * 128;
  const ush* gB = wsel == 0 ? Wqb : wsel == 1 ? Wkb : Wvb;
  const float* bias = wsel == 0 ? bq : wsel == 1 ? bk : bv;
  const float oscale = wsel == 1 ? 0.180336880f : 1.0f;  // 0.125*log2e on K

  __shared__ alignas(16) ush lA[128 * 64];
  __shared__ alignas(16) ush lB[128 * 64];
  f32x4 acc[4][4];
  gemm128_core(xb, gB, m0, n0, lA, lB, acc);

  const int t = threadIdx.x, w = t >> 6, lane = t & 63;
  const int l15 = lane & 15, quad = lane >> 4;
  const int wm = (w >> 1) * 64, wn = (w & 1) * 64;
  if (wsel == 2) {
    // V^T with permuted column order; 4 consecutive s -> 4 consecutive p
#pragma unroll
    for (int nt = 0; nt < 4; ++nt) {
      int o = n0 + wn + nt * 16 + l15;
      float bl = bias[o];
      int h = o >> 6, d = o & 63;
#pragma unroll
      for (int mt = 0; mt < 4; ++mt) {
        int tb = m0 + wm + mt * 16 + quad * 4;
        int b = tb >> 11, s = tb & 2047;
        int so = s & 63;
        int sp = (s & ~63) | (so & 35) | ((so & 12) << 1) | ((so & 16) >> 2);
        u16x4 pk = { f2bf(acc[mt][nt][0] + bl), f2bf(acc[mt][nt][1] + bl),
                     f2bf(acc[mt][nt][2] + bl), f2bf(acc[mt][nt][3] + bl) };
        *(u16x4*)(vt + (size_t)(((b * 16 + h) * 64) + d) * 2048 + sp) = pk;
      }
    }
  } else {
    ush* dst = wsel == 0 ? q : k;
#pragma unroll
    for (int nt = 0; nt < 4; ++nt) {
      int o = n0 + wn + nt * 16 + l15;
      float bl = bias[o];
      int h = o >> 6, d = o & 63;
#pragma unroll
      for (int mt = 0; mt < 4; ++mt)
#pragma unroll
        for (int r = 0; r < 4; ++r) {
          int token = m0 + wm + mt * 16 + quad * 4 + r;
          int b = token >> 11, s = token & 2047;
          dst[(size_t)(((b * 16 + h) * 2048) + s) * 64 + d] =
              f2bf((acc[mt][nt][r] + bl) * oscale);
        }
    }
  }
}

// ---------------- flash attention (S^T, 32 queries/wave) ----------------
// 1024 blocks = 32 bh x 32 q-tiles of 64 rows; 2 waves x 32 queries each
// (two 16-query groups share every K/V LDS fragment -> half the LDS reads).
// Block swizzle: all q-tiles of one bh share blockIdx%8 -> same XCD L2.
// PV: O^T = V^T·P^T with permuted contraction keys; V stored permuted so the
// A-fragment is one b128; exps pack in-register into the B-fragment.
__global__ __launch_bounds__(128, 2) void attn_kernel(
    const ush* __restrict__ Q, const ush* __restrict__ K,
    const ush* __restrict__ VT, ush* __restrict__ O)
{
  const int bid = blockIdx.x;
  const int bh = (bid & 7) * 4 + (bid >> 8);   // same bh -> same XCD residue
  const int qt = (bid >> 3) & 31;
  const ush* qb = Q + (size_t)bh * 2048 * 64;
  const ush* kb = K + (size_t)bh * 2048 * 64;
  const ush* vtb = VT + (size_t)bh * 64 * 2048;   // [d][p(s)]
  const int t = threadIdx.x, w = t >> 6, lane = t & 63;
  const int l15 = lane & 15, quad = lane >> 4;
  const int q0 = qt * 64 + w * 32;        // this wave's 32 queries (2 groups)

  __shared__ alignas(16) ush lK[2][64 * 64];     // [key][d], swizzled chunks
  __shared__ alignas(16) ush lV[2][64 * 64];     // [d][p(key)], swizzled chunks

  // staging: 512 chunks per tensor, 128 threads -> 4 chunks each.
  // chunk j = i*128 + t: row = i*16 + (t>>3), col c0 = (t&7)^(row&7)
  const int r0 = t >> 3;
  const int c0 = (t & 7) ^ (r0 & 7);
  const ush* kSrc = kb + (size_t)r0 * 64 + c0 * 8;      // +i*1024
  const ush* vSrc = vtb + (size_t)r0 * 2048 + c0 * 8;   // +i*16*2048

  // Q fragments (B-operand: n=q=l15, k=d), 2 groups x 2 kf
  bf16x8 qF[2][2];
#pragma unroll
  for (int g = 0; g < 2; ++g)
#pragma unroll
    for (int kf = 0; kf < 2; ++kf)
      qF[g][kf] = bc8(*(const u16x8*)(qb + (size_t)(q0 + g * 16 + l15) * 64 +
                                      kf * 32 + quad * 8));

  float li[2] = {0.f, 0.f};
  f32x4 accO[2][4];                       // O^T: [d=dt*16+quad*4+r][q=l15]
#pragma unroll
  for (int g = 0; g < 2; ++g)
#pragma unroll
    for (int dt = 0; dt < 4; ++dt) accO[g][dt] = (f32x4){0.f, 0.f, 0.f, 0.f};

  // prologue: DMA tile 0 into buffer 0
#pragma unroll
  for (int i = 0; i < 4; ++i) {
    async16(kSrc + i * 1024, lK[0] + (i * 128 + t) * 8);
    async16(vSrc + (size_t)i * 16 * 2048, lV[0] + (i * 128 + t) * 8);
  }
  __syncthreads();                       // vmcnt drain = DMA complete

  for (int it = 0; it < 32; ++it) {
    const int cur = it & 1, nxt = cur ^ 1;
    if (it + 1 < 32) {                   // DMA next tile while computing this one
      const size_t ko = (size_t)(it + 1) * 64 * 64;   // K advances by rows
      const int vo = (it + 1) * 64;                   // V^T advances by cols
#pragma unroll
      for (int i = 0; i < 4; ++i) {
        async16(kSrc + ko + i * 1024, lK[nxt] + (i * 128 + t) * 8);
        async16(vSrc + vo + (size_t)i * 16 * 2048, lV[nxt] + (i * 128 + t) * 8);
      }
    }
    const ush* lk = lK[cur];
    const ush* lv = lV[cur];

    // S^T = K·Q^T : A=K (m=key), B=Q (n=q). C: row=key=mt*16+quad*4+r, col=q
    f32x4 sc[2][4];
#pragma unroll
    for (int g = 0; g < 2; ++g)
#pragma unroll
      for (int mt = 0; mt < 4; ++mt) sc[g][mt] = (f32x4){0.f, 0.f, 0.f, 0.f};
#pragma unroll
    for (int kf = 0; kf < 2; ++kf) {
#pragma unroll
      for (int mt = 0; mt < 4; ++mt) {
        int row = mt * 16 + l15;
        bf16x8 aK = bc8(*(const u16x8*)(lk + row * 64 + (((kf * 4 + quad) ^ (row & 7)) * 8)));
#pragma unroll
        for (int g = 0; g < 2; ++g)
          sc[g][mt] = __builtin_amdgcn_mfma_f32_16x16x32_bf16(
              aK, qF[g][kf], sc[g][mt], 0, 0, 0);
      }
    }

    // softmax: raw v_exp (args bounded; K pre-scaled), in-place
    float rs[2] = {0.f, 0.f};
#pragma unroll
    for (int g = 0; g < 2; ++g) {
#pragma unroll
      for (int mt = 0; mt < 4; ++mt)
#pragma unroll
        for (int r = 0; r < 4; ++r) {
          sc[g][mt][r] = __builtin_amdgcn_exp2f(sc[g][mt][r]);
          rs[g] += sc[g][mt][r];
        }
      rs[g] += __shfl_xor(rs[g], 16);
      rs[g] += __shfl_xor(rs[g], 32);
      li[g] += rs[g];
    }

    // PV: O^T = V^T·P^T; contraction key sigma(quad*8+j)=2ks*16+(j>>2)*16+
    // quad*4+(j&3) <-> V position ks*32+quad*8+j (contiguous b128).
#pragma unroll
    for (int ks = 0; ks < 2; ++ks) {
      bf16x8 aV[4];
#pragma unroll
      for (int dt = 0; dt < 4; ++dt)
        aV[dt] = bc8(*(const u16x8*)(lv + (dt * 16 + l15) * 64 +
                                     (((ks * 4 + quad) ^ (l15 & 7)) * 8)));
#pragma unroll
      for (int g = 0; g < 2; ++g) {
        u32x4 bw = { pack2bf_ru(sc[g][2 * ks][0],     sc[g][2 * ks][1]),
                     pack2bf_ru(sc[g][2 * ks][2],     sc[g][2 * ks][3]),
                     pack2bf_ru(sc[g][2 * ks + 1][0], sc[g][2 * ks + 1][1]),
                     pack2bf_ru(sc[g][2 * ks + 1][2], sc[g][2 * ks + 1][3]) };
        bf16x8 bP = __builtin_bit_cast(bf16x8, bw);
#pragma unroll
        for (int dt = 0; dt < 4; ++dt)
          accO[g][dt] = __builtin_amdgcn_mfma_f32_16x16x32_bf16(
              aV[dt], bP, accO[g][dt], 0, 0, 0);
      }
    }
    __syncthreads();   // all reads of cur done + next-tile DMA drained
  }

  // epilogue: O[q][d] = accO^T/li, packed u16x4 stores to [B,S,D]
  const int b = bh >> 4, h = bh & 15;
#pragma unroll
  for (int g = 0; g < 2; ++g) {
    const float linv = __builtin_amdgcn_rcpf(li[g]);
    const int s = q0 + g * 16 + l15;
#pragma unroll
    for (int dt = 0; dt < 4; ++dt) {
      u16x4 pk = { f2bf(accO[g][dt][0] * linv), f2bf(accO[g][dt][1] * linv),
                   f2bf(accO[g][dt][2] * linv), f2bf(accO[g][dt][3] * linv) };
      *(u16x4*)(O + (size_t)(b * 2048 + s) * 1024 + h * 64 + dt * 16 + quad * 4) = pk;
    }
  }
}

// ---------------- output projection (fp32 out) ----------------
__global__ __launch_bounds__(256, 2) void out_gemm(
    const ush* __restrict__ ab, const ush* __restrict__ Wob,
    const float* __restrict__ bo, float* __restrict__ out)
{
  int rem = blockIdx.x;
  int m0 = (rem & 31) * 128;
  int n0 = (rem >> 5) * 128;
  __shared__ alignas(16) ush lA[128 * 64];
  __shared__ alignas(16) ush lB[128 * 64];
  f32x4 acc[4][4];
  gemm128_core(ab, Wob, m0, n0, lA, lB, acc);

  const int t = threadIdx.x, w = t >> 6, lane = t & 63;
  const int l15 = lane & 15, quad = lane >> 4;
  const int wm = (w >> 1) * 64, wn = (w & 1) * 64;
#pragma unroll
  for (int nt = 0; nt < 4; ++nt) {
    int o = n0 + wn + nt * 16 + l15;
    float bl = bo[o];
#pragma unroll
    for (int mt = 0; mt < 4; ++mt)
#pragma unroll
      for (int r = 0; r < 4; ++r) {
        int token = m0 + wm + mt * 16 + quad * 4 + r;
        out[(size_t)token * 1024 + o] = acc[mt][nt][r] + bl;
      }
  }
}

extern "C" void kernel_launch(void* const* d_in, const int* in_sizes, int n_in,
                              void* d_out, int out_size, void* d_ws, size_t ws_size,
                              hipStream_t stream)
{
  const float* x  = (const float*)d_in[0];
  const float* Wq = (const float*)d_in[1];
  const float* bq = (const float*)d_in[2];
  const float* Wk = (const float*)d_in[3];
  const float* bk = (const float*)d_in[4];
  const float* Wv = (const float*)d_in[5];
  const float* bv = (const float*)d_in[6];
  const float* Wo = (const float*)d_in[7];
  const float* bo = (const float*)d_in[8];
  float* out = (float*)d_out;

  char* ws = (char*)d_ws;
  ush* xb  = (ush*)(ws);                      // 8 MiB  [4096 x 1024]
  ush* Wqb = (ush*)(ws + (size_t)( 8u << 20));// 2 MiB each
  ush* Wkb = (ush*)(ws + (size_t)(10u << 20));
  ush* Wvb = (ush*)(ws + (size_t)(12u << 20));
  ush* Wob = (ush*)(ws + (size_t)(14u << 20));
  ush* qb  = (ush*)(ws + (size_t)(16u << 20));// 8 MiB [B,H,S,64]
  ush* kb  = (ush*)(ws + (size_t)(24u << 20));
  ush* vtb = (ush*)(ws + (size_t)(32u << 20));// 8 MiB [B,H,64,S] perm cols
  ush* ab  = (ush*)(ws + (size_t)(40u << 20));// 8 MiB [B,S,D] attn out (bf16)

  convert_kernel<<<8192, 256, 0, stream>>>(x, Wq, Wk, Wv, Wo,
                                           xb, Wqb, Wkb, Wvb, Wob);
  qkv_gemm<<<768, 256, 0, stream>>>(xb, Wqb, Wkb, Wvb, bq, bk, bv, qb, kb, vtb);
  attn_kernel<<<1024, 128, 0, stream>>>(qb, kb, vtb, ab);
  out_gemm<<<256, 256, 0, stream>>>(ab, Wob, bo, out);
}